// Round 6
// baseline (112.567 us; speedup 1.0000x reference)
//
#include <hip/hip_runtime.h>
#include <hip/hip_bf16.h>

// SNNonLocalBlock: B=16, H=W=64, C=256, L=4096, Ld=1024
// Round 6: k_attn = 4 waves x 2 q-tiles (128 q/block, 512 blocks) so every
// g/phi B-frag feeds 2 MFMA; g_pT m-order permuted in k_pool so each PV
// B-frag is ONE ds_read_b128. LDS = 40KB exactly -> 4 blocks/CU.

typedef __attribute__((ext_vector_type(8))) short bf16x8;
typedef __attribute__((ext_vector_type(4))) float f32x4;

#define MFMA16(A,B,C) __builtin_amdgcn_mfma_f32_16x16x32_bf16(A,B,C,0,0,0)

#define GLOAD16(GSRC, LDST)                                                        \
    __builtin_amdgcn_global_load_lds(                                              \
        (const __attribute__((address_space(1))) unsigned int*)(GSRC),             \
        (__attribute__((address_space(3))) unsigned int*)(LDST), 16, 0, 0)

static __device__ __forceinline__ unsigned short f2b(float f) {
    __hip_bfloat16 h = __float2bfloat16(f);
    return *reinterpret_cast<unsigned short*>(&h);
}
static __device__ __forceinline__ float blo(unsigned int u){ return __uint_as_float(u << 16); }
static __device__ __forceinline__ float bhi(unsigned int u){ return __uint_as_float(u & 0xffff0000u); }

// ---------------------------------------------------------------------------
// K0: prep: WT[192 n][256 k] bf16 = [w_theta|w_phi|w_g]^T ; woT[256 c][128 d] bf16
// ---------------------------------------------------------------------------
__global__ void k_prep(const float* __restrict__ w_theta, const float* __restrict__ w_phi,
                       const float* __restrict__ w_g, const float* __restrict__ w_o,
                       unsigned short* __restrict__ WT, unsigned short* __restrict__ woT)
{
    int bid = blockIdx.x, t = threadIdx.x;
    if (bid < 192) {
        int n = bid;
        float v;
        if (n < 32)      v = w_theta[t * 32 + n];
        else if (n < 64) v = w_phi[t * 32 + (n - 32)];
        else             v = w_g[t * 128 + (n - 64)];
        WT[n * 256 + t] = f2b(v);
    } else if (t < 128) {
        int cc = bid - 192;
        woT[cc * 128 + t] = f2b(w_o[t * 256 + cc]);
    }
}

// ---------------------------------------------------------------------------
// K1: proj MFMA: out[65536,192] = x @ W. 128-row blocks, BK=64, 4 waves.
// ---------------------------------------------------------------------------
__global__ __launch_bounds__(256) void k_proj(
    const float* __restrict__ x, const unsigned short* __restrict__ WT,
    unsigned short* __restrict__ theta_b, unsigned short* __restrict__ phi_b,
    unsigned short* __restrict__ g_b)
{
    __shared__ unsigned short xT[128 * 64];   // [m][64k] swizzled, 16KB
    __shared__ unsigned short wT[192 * 64];   // [n][64k] swizzled, 24KB
    const int t = threadIdx.x;
    const int w = t >> 6, l = t & 63, G = l >> 4, c = l & 15;
    const size_t row0 = (size_t)blockIdx.x * 128;

    f32x4 acc[2][12];
#pragma unroll
    for (int i = 0; i < 2; i++)
#pragma unroll
        for (int j = 0; j < 12; j++) acc[i][j] = (f32x4){0.f, 0.f, 0.f, 0.f};

    for (int k0 = 0; k0 < 256; k0 += 64) {
        __syncthreads();
#pragma unroll
        for (int it = 0; it < 4; it++) {           // x tile: 128 rows x 8 slots
            int u = it * 256 + t, r = u >> 3, s = u & 7;
            const float* px = x + (row0 + r) * 256 + k0 + s * 8;
            float4 a = *(const float4*)px;
            float4 bq = *(const float4*)(px + 4);
            uint4 v;
            v.x = (unsigned)f2b(a.x) | ((unsigned)f2b(a.y) << 16);
            v.y = (unsigned)f2b(a.z) | ((unsigned)f2b(a.w) << 16);
            v.z = (unsigned)f2b(bq.x) | ((unsigned)f2b(bq.y) << 16);
            v.w = (unsigned)f2b(bq.z) | ((unsigned)f2b(bq.w) << 16);
            *(uint4*)((char*)xT + r * 128 + ((s * 16) ^ ((r & 7) << 4))) = v;
        }
#pragma unroll
        for (int it = 0; it < 6; it++) {           // W tile: 192 rows x 8 slots
            int u = it * 256 + t, r = u >> 3, s = u & 7;
            uint4 v = *(const uint4*)(WT + r * 256 + k0 + s * 8);
            *(uint4*)((char*)wT + r * 128 + ((s * 16) ^ ((r & 7) << 4))) = v;
        }
        __syncthreads();
#pragma unroll
        for (int kin = 0; kin < 2; kin++) {
            int m0r = (2 * w) * 16 + c, m1r = (2 * w + 1) * 16 + c;
            bf16x8 a0 = *(const bf16x8*)((char*)xT + m0r * 128 + ((kin * 64 + G * 16) ^ ((m0r & 7) << 4)));
            bf16x8 a1 = *(const bf16x8*)((char*)xT + m1r * 128 + ((kin * 64 + G * 16) ^ ((m1r & 7) << 4)));
#pragma unroll
            for (int nt = 0; nt < 12; nt++) {
                int nr = nt * 16 + c;
                bf16x8 bv = *(const bf16x8*)((char*)wT + nr * 128 + ((kin * 64 + G * 16) ^ ((nr & 7) << 4)));
                acc[0][nt] = MFMA16(a0, bv, acc[0][nt]);
                acc[1][nt] = MFMA16(a1, bv, acc[1][nt]);
            }
        }
    }
#pragma unroll
    for (int mt = 0; mt < 2; mt++)
#pragma unroll
        for (int nt = 0; nt < 12; nt++)
#pragma unroll
            for (int i = 0; i < 4; i++) {
                size_t row = row0 + (2 * w + mt) * 16 + 4 * G + i;
                unsigned short v = f2b(acc[mt][nt][i]);
                if (nt < 2)      theta_b[row * 32 + nt * 16 + c] = v;
                else if (nt < 4) phi_b[row * 32 + (nt - 2) * 16 + c] = v;
                else             g_b[row * 128 + (nt - 4) * 16 + c] = v;
            }
}

// ---------------------------------------------------------------------------
// K2: pool. blocks [0,1024): phi -> phi_p [b][1024][32] pre-swizzled
//            (16B blk within 64B row XOR'd by (m&3))
//          blocks [1024,1536): g -> pooled, transposed, m-PERMUTED g_pT:
//            within each 32-m group, pos p = 8*gg + 4*h + i for m=16h+4gg+i
//            (so a PV B-frag = 16 contiguous bytes), then 16B-block XOR (d&7).
// ---------------------------------------------------------------------------
__global__ __launch_bounds__(256) void k_pool(
    const unsigned short* __restrict__ phi_b, const unsigned short* __restrict__ g_b,
    unsigned short* __restrict__ phi_p, unsigned short* __restrict__ g_pT)
{
    const int bid = blockIdx.x, t = threadIdx.x;
    if (bid < 1024) {
        const unsigned int* p32 = (const unsigned int*)phi_b;
        unsigned int* pp32 = (unsigned int*)phi_p;
        int idx = bid * 256 + t;
        int b = idx >> 14, r = idx & 16383, pm = r >> 4, d2 = r & 15;
        int hp = pm >> 5, wp = pm & 31;
        size_t base = ((size_t)b * 4096 + (2 * hp) * 64 + 2 * wp) * 16 + d2;
        unsigned v0 = p32[base], v1 = p32[base + 16], v2 = p32[base + 1024], v3 = p32[base + 1040];
        float lo = fmaxf(fmaxf(blo(v0), blo(v1)), fmaxf(blo(v2), blo(v3)));
        float hi = fmaxf(fmaxf(bhi(v0), bhi(v1)), fmaxf(bhi(v2), bhi(v3)));
        pp32[(idx & ~15) | (d2 ^ ((pm & 3) << 2))] =
            (unsigned)f2b(lo) | ((unsigned)f2b(hi) << 16);
    } else {
        __shared__ unsigned short P[32 * 128];   // [wp][128 d], rows 256B, swz key (wp&7)<<4
        int b = (bid - 1024) >> 5, hp = (bid - 1024) & 31;
        const unsigned int* g32 = (const unsigned int*)g_b;
#pragma unroll
        for (int it = 0; it < 8; it++) {
            int u = it * 256 + t, wp = u >> 6, d2 = u & 63;
            size_t base = ((size_t)b * 4096 + (2 * hp) * 64 + 2 * wp) * 64 + d2;
            unsigned v0 = g32[base], v1 = g32[base + 64], v2 = g32[base + 4096], v3 = g32[base + 4160];
            float lo = fmaxf(fmaxf(blo(v0), blo(v1)), fmaxf(blo(v2), blo(v3)));
            float hi = fmaxf(fmaxf(bhi(v0), bhi(v1)), fmaxf(bhi(v2), bhi(v3)));
            unsigned pv = (unsigned)f2b(lo) | ((unsigned)f2b(hi) << 16);
            *(unsigned*)((char*)P + wp * 256 + ((d2 * 4) ^ ((wp & 7) << 4))) = pv;
        }
        __syncthreads();
#pragma unroll
        for (int it = 0; it < 2; it++) {
            int d = t & 127, s4 = (t >> 7) + it * 2;   // s4 = gg (position block)
            union { unsigned short v[8]; uint4 q; } pk;
#pragma unroll
            for (int k = 0; k < 8; k++) {
                // position p = s4*8 + k holds m_local = 16*(k>>2) + 4*s4 + (k&3)
                int wp = 16 * (k >> 2) + 4 * s4 + (k & 3);
                pk.v[k] = *(const unsigned short*)((char*)P + wp * 256 + ((d * 2) ^ ((wp & 7) << 4)));
            }
            int midx = (hp * 32 + s4 * 8) ^ ((d & 7) << 3);   // 16B-block XOR pre-swizzle
            *(uint4*)(g_pT + ((size_t)b * 128 + d) * 1024 + midx) = pk.q;
        }
    }
}

// ---------------------------------------------------------------------------
// K3: fused flash attention. 256 threads = 4 waves x 2 q-tiles (128 q/block),
// 16 m-chunks of 64. global_load_lds dbuf, counted vmcnt(5)/wave.
// ---------------------------------------------------------------------------
__global__ __launch_bounds__(256, 4) void k_attn(
    const unsigned short* __restrict__ theta_b, const unsigned short* __restrict__ phi_p,
    const unsigned short* __restrict__ g_pT, const unsigned short* __restrict__ woT,
    const float* __restrict__ x, const float* __restrict__ b_o,
    const float* __restrict__ sigma_p, float* __restrict__ out)
{
    // main: buf bi @ bi*20480: g[128 rows x 128B] | phi @+16384 [64 x 64B]
    // theta prologue @20480 [128 x 64B]. Epilogue: O half h @ h*16384 [64q x 256B],
    // wo_l @32768 [32c x 256B]. Total 40960.
    __shared__ char lds[40960];

    const int t = threadIdx.x;
    const int w = t >> 6, l = t & 63, G = l >> 4, c = l & 15;
    const int bid = (blockIdx.x & 7) * 64 + (blockIdx.x >> 3);   // XCD swizzle (512%8==0)
    const int b = bid >> 5;
    const int q0 = (bid & 31) * 128;
    const int xr = (c & 7) << 4;       // 128B/256B-row swizzle key
    const int xr3 = (c & 3) << 4;      // 64B-row swizzle key

    const unsigned short* gsrc_base = g_pT + (size_t)b * 131072;
    const unsigned short* psrc_base = phi_p + (size_t)b * 32768;
    // per wave per chunk: 4 g-loads + 1 phi-load -> counted vmcnt(5)
#define STAGE(BI, MCN)                                                                  \
    {                                                                                   \
        char* gb = lds + (BI) * 20480;                                                  \
        char* pb = gb + 16384;                                                          \
        _Pragma("unroll")                                                               \
        for (int it = 0; it < 4; it++) {                                                \
            int d = 32 * it + 8 * w + (l >> 3), s = l & 7;                              \
            GLOAD16(gsrc_base + (size_t)d * 1024 + (MCN) * 64 + s * 8,                  \
                    gb + it * 4096 + w * 1024);                                         \
        }                                                                               \
        {                                                                               \
            int r = 16 * w + (l >> 2), s = l & 3;                                       \
            GLOAD16(psrc_base + (size_t)((MCN) * 64 + r) * 32 + s * 8,                  \
                    pb + w * 1024);                                                     \
        }                                                                               \
    }

    // prologue: stage chunk 0 + theta [128 q][32 k] (in buf1 g region, 64B rows)
    STAGE(0, 0);
    {
        char* th = lds + 20480;
#pragma unroll
        for (int it = 0; it < 2; it++) {
            int u = it * 256 + t, r = u >> 2, s = u & 3;
            uint4 v = *(const uint4*)(theta_b + ((size_t)(b * 4096 + q0 + r)) * 32 + s * 8);
            *(uint4*)(th + r * 64 + ((s * 16) ^ ((r & 3) << 4))) = v;
        }
    }
    __syncthreads();   // drains vmcnt+lgkm: chunk0 + theta in LDS

    // wave w's theta B-frags: q-tiles at w*32 and w*32+16
    bf16x8 bt0, bt1;
    {
        const char* th = lds + 20480;
        bt0 = *(const bf16x8*)(th + (w * 32 + c) * 64 + ((G * 16) ^ xr3));
        bt1 = *(const bf16x8*)(th + (w * 32 + 16 + c) * 64 + ((G * 16) ^ xr3));
    }
    __syncthreads();   // bt reads complete before iter0 stages buf1

    f32x4 oacc[2][8];
#pragma unroll
    for (int qt = 0; qt < 2; qt++)
#pragma unroll
        for (int dt = 0; dt < 8; dt++) oacc[qt][dt] = (f32x4){0.f, 0.f, 0.f, 0.f};
    float ps[2] = {0.f, 0.f};
    const f32x4 zf = (f32x4){0.f, 0.f, 0.f, 0.f};

    for (int mc = 0; mc < 16; mc++) {
        const int cur = mc & 1;
        if (mc < 15) {
            STAGE(cur ^ 1, mc + 1);
            asm volatile("s_waitcnt vmcnt(5)" ::: "memory");   // cur's 5 landed
        } else {
            asm volatile("s_waitcnt vmcnt(0)" ::: "memory");
        }
        __builtin_amdgcn_sched_barrier(0);
        __builtin_amdgcn_s_barrier();
        __builtin_amdgcn_sched_barrier(0);

        const char* gL   = lds + cur * 20480;
        const char* phiL = gL + 16384;

        // S^T = phi @ theta^T : lane (G,c) gets S[m=mt*16+4G+i][q=c] per tile
        bf16x8 ap[4];
#pragma unroll
        for (int mt = 0; mt < 4; mt++)
            ap[mt] = *(const bf16x8*)(phiL + (mt * 16 + c) * 64 + ((G * 16) ^ xr3));
        f32x4 sacc[2][4];
        __builtin_amdgcn_s_setprio(1);
#pragma unroll
        for (int mt = 0; mt < 4; mt++) {
            sacc[0][mt] = MFMA16(ap[mt], bt0, zf);
            sacc[1][mt] = MFMA16(ap[mt], bt1, zf);
        }
        __builtin_amdgcn_s_setprio(0);

        // exp -> packed P A-frags + rowsum partials (no max-sub: |S| << 88)
        bf16x8 pa[2][2];
#pragma unroll
        for (int qt = 0; qt < 2; qt++)
#pragma unroll
            for (int ks = 0; ks < 2; ks++) {
                union { unsigned u[4]; bf16x8 v; } pu;
#pragma unroll
                for (int hf = 0; hf < 2; hf++) {
                    int mt = 2 * ks + hf;
                    float p0 = __expf(sacc[qt][mt][0]);
                    float p1 = __expf(sacc[qt][mt][1]);
                    float p2 = __expf(sacc[qt][mt][2]);
                    float p3 = __expf(sacc[qt][mt][3]);
                    ps[qt] += (p0 + p1) + (p2 + p3);
                    pu.u[hf * 2]     = (unsigned)f2b(p0) | ((unsigned)f2b(p1) << 16);
                    pu.u[hf * 2 + 1] = (unsigned)f2b(p2) | ((unsigned)f2b(p3) << 16);
                }
                pa[qt][ks] = pu.v;
            }

        // O += P @ g   (B-frag = ONE b128: m-order pre-permuted in k_pool)
        __builtin_amdgcn_s_setprio(1);
#pragma unroll
        for (int ks = 0; ks < 2; ks++) {
#pragma unroll
            for (int dt = 0; dt < 8; dt++) {
                bf16x8 bg = *(const bf16x8*)(gL + (dt * 16 + c) * 128 + ((64 * ks + 16 * G) ^ xr));
                oacc[0][dt] = MFMA16(pa[0][ks], bg, oacc[0][dt]);
                oacc[1][dt] = MFMA16(pa[1][ks], bg, oacc[1][dt]);
            }
        }
        __builtin_amdgcn_s_setprio(0);

        asm volatile("s_waitcnt lgkmcnt(0)" ::: "memory");  // cur reads done
        __builtin_amdgcn_sched_barrier(0);
        __builtin_amdgcn_s_barrier();                       // safe to overwrite cur
        __builtin_amdgcn_sched_barrier(0);
    }
#undef STAGE

    // rowsums: lanes {c, c+16, c+32, c+48} hold partials for q-col c
#pragma unroll
    for (int qt = 0; qt < 2; qt++) {
        ps[qt] += __shfl_xor(ps[qt], 16);
        ps[qt] += __shfl_xor(ps[qt], 32);
    }
    float rinv[2][4];
#pragma unroll
    for (int qt = 0; qt < 2; qt++)
#pragma unroll
        for (int i = 0; i < 4; i++)
            rinv[qt][i] = 1.0f / __shfl(ps[qt], 4 * G + i);

    // normalized O -> O half (w>>1) @ (w>>1)*16384: [64 local q][128 d] bf16
    {
        char* O_h = lds + (w >> 1) * 16384;
#pragma unroll
        for (int qt = 0; qt < 2; qt++)
#pragma unroll
            for (int dt = 0; dt < 8; dt++)
#pragma unroll
                for (int i = 0; i < 4; i++) {
                    int ql = (w & 1) * 32 + qt * 16 + 4 * G + i, d = dt * 16 + c;
                    *(unsigned short*)(O_h + ql * 256 + ((d * 2) ^ ((ql & 7) << 4))) =
                        f2b(oacc[qt][dt][i] * rinv[qt][i]);
                }
    }

    const float sg = *sigma_p;
    const char* O_h = lds + (w >> 1) * 16384;
    char* wo_l = lds + 32768;
    const int arow0 = ((w & 1) * 32 + c) * 256;
    const int arow1 = ((w & 1) * 32 + 16 + c) * 256;

    for (int cb = 0; cb < 8; cb++) {
        __syncthreads();                            // O visible / prev wo_l reads done
#pragma unroll
        for (int it = 0; it < 2; it++) {            // stage woT 32-row slice [32 c][128 d]
            int u = it * 256 + t, r = u >> 4, s = u & 15;
            uint4 v = *(const uint4*)(woT + (size_t)(cb * 32 + r) * 128 + s * 8);
            *(uint4*)(wo_l + r * 256 + ((s * 16) ^ ((r & 7) << 4))) = v;
        }
        __syncthreads();
        f32x4 eacc[2][2];
#pragma unroll
        for (int qt = 0; qt < 2; qt++)
#pragma unroll
            for (int ct = 0; ct < 2; ct++) eacc[qt][ct] = (f32x4){0.f, 0.f, 0.f, 0.f};
#pragma unroll
        for (int ks = 0; ks < 4; ks++) {
            bf16x8 a0 = *(const bf16x8*)(O_h + arow0 + ((ks * 64 + G * 16) ^ xr));
            bf16x8 a1 = *(const bf16x8*)(O_h + arow1 + ((ks * 64 + G * 16) ^ xr));
#pragma unroll
            for (int ct = 0; ct < 2; ct++) {
                bf16x8 bw = *(const bf16x8*)(wo_l + (ct * 16 + c) * 256 + ((ks * 64 + G * 16) ^ xr));
                eacc[0][ct] = MFMA16(a0, bw, eacc[0][ct]);
                eacc[1][ct] = MFMA16(a1, bw, eacc[1][ct]);
            }
        }
#pragma unroll
        for (int qt = 0; qt < 2; qt++)
#pragma unroll
            for (int ct = 0; ct < 2; ct++) {
                int col = cb * 32 + ct * 16 + c;
                float bo = b_o[col];
#pragma unroll
                for (int i = 0; i < 4; i++) {
                    size_t off = ((size_t)(b * 4096 + q0 + w * 32 + qt * 16 + 4 * G + i)) * 256 + col;
                    out[off] = x[off] + sg * (eacc[qt][ct][i] + bo);
                }
            }
    }
}

// ---------------------------------------------------------------------------
extern "C" void kernel_launch(void* const* d_in, const int* in_sizes, int n_in,
                              void* d_out, int out_size, void* d_ws, size_t ws_size,
                              hipStream_t stream)
{
    const float* x       = (const float*)d_in[0];
    const float* w_theta = (const float*)d_in[1];
    const float* w_phi   = (const float*)d_in[2];
    const float* w_g     = (const float*)d_in[3];
    const float* w_o     = (const float*)d_in[4];
    const float* b_o     = (const float*)d_in[5];
    const float* sigma   = (const float*)d_in[6];
    float* out = (float*)d_out;

    char* ws = (char*)d_ws;
    unsigned short* theta_b = (unsigned short*)(ws);              //  4 MB [B,4096,32]
    unsigned short* phi_b   = (unsigned short*)(ws + 4194304);    //  4 MB [B,4096,32]
    unsigned short* g_b     = (unsigned short*)(ws + 8388608);    // 16 MB [B,4096,128]
    unsigned short* phi_p   = (unsigned short*)(ws + 25165824);   //  1 MB [B,1024,32] pre-swz
    unsigned short* g_pT    = (unsigned short*)(ws + 26214400);   //  4 MB [B,128,1024] perm+swz
    unsigned short* WT      = (unsigned short*)(ws + 30408704);   // 96 KB [192,256]
    unsigned short* woT     = (unsigned short*)(ws + 30507008);   // 64 KB [256,128]

    hipLaunchKernelGGL(k_prep, dim3(448), dim3(256), 0, stream,
                       w_theta, w_phi, w_g, w_o, WT, woT);
    hipLaunchKernelGGL(k_proj, dim3(512), dim3(256), 0, stream,
                       x, WT, theta_b, phi_b, g_b);
    hipLaunchKernelGGL(k_pool, dim3(1536), dim3(256), 0, stream,
                       phi_b, g_b, phi_p, g_pT);
    hipLaunchKernelGGL(k_attn, dim3(512), dim3(256), 0, stream,
                       theta_b, phi_p, g_pT, woT, x, b_o, sigma, out);
}

// Round 7
// 77.463 us; speedup vs baseline: 1.4532x; 1.4532x over previous
//
#include <hip/hip_runtime.h>
#include <hip/hip_bf16.h>

// SNNonLocalBlock: B=16, H=W=64, C=256, L=4096, Ld=1024
// Round 7: k_attn = 1024 blocks x 4 waves (2 q-groups x 2 m-groups).
// Each wave: 32q x 512m (16 chunks of 32m), qtpw=2 B-frag amortization,
// 16 waves/CU. Chunk=32m => all main-loop LDS reads are dense conflict-free
// sweeps (no swizzle). m-group partials combined in LDS (f32, stride 520).

typedef __attribute__((ext_vector_type(8))) short bf16x8;
typedef __attribute__((ext_vector_type(4))) float f32x4;

#define MFMA16(A,B,C) __builtin_amdgcn_mfma_f32_16x16x32_bf16(A,B,C,0,0,0)

#define GLOAD16(GSRC, LDST)                                                        \
    __builtin_amdgcn_global_load_lds(                                              \
        (const __attribute__((address_space(1))) unsigned int*)(GSRC),             \
        (__attribute__((address_space(3))) unsigned int*)(LDST), 16, 0, 0)

static __device__ __forceinline__ unsigned short f2b(float f) {
    __hip_bfloat16 h = __float2bfloat16(f);
    return *reinterpret_cast<unsigned short*>(&h);
}
static __device__ __forceinline__ float blo(unsigned int u){ return __uint_as_float(u << 16); }
static __device__ __forceinline__ float bhi(unsigned int u){ return __uint_as_float(u & 0xffff0000u); }

// ---------------------------------------------------------------------------
// K0: prep: WT[192 n][256 k] bf16 = [w_theta|w_phi|w_g]^T ; woT[256 c][128 d] bf16
// ---------------------------------------------------------------------------
__global__ void k_prep(const float* __restrict__ w_theta, const float* __restrict__ w_phi,
                       const float* __restrict__ w_g, const float* __restrict__ w_o,
                       unsigned short* __restrict__ WT, unsigned short* __restrict__ woT)
{
    int bid = blockIdx.x, t = threadIdx.x;
    if (bid < 192) {
        int n = bid;
        float v;
        if (n < 32)      v = w_theta[t * 32 + n];
        else if (n < 64) v = w_phi[t * 32 + (n - 32)];
        else             v = w_g[t * 128 + (n - 64)];
        WT[n * 256 + t] = f2b(v);
    } else if (t < 128) {
        int cc = bid - 192;
        woT[cc * 128 + t] = f2b(w_o[t * 256 + cc]);
    }
}

// ---------------------------------------------------------------------------
// K1: proj MFMA: out[65536,192] = x @ W. 128-row blocks, BK=64, 4 waves.
// ---------------------------------------------------------------------------
__global__ __launch_bounds__(256) void k_proj(
    const float* __restrict__ x, const unsigned short* __restrict__ WT,
    unsigned short* __restrict__ theta_b, unsigned short* __restrict__ phi_b,
    unsigned short* __restrict__ g_b)
{
    __shared__ unsigned short xT[128 * 64];   // [m][64k] swizzled, 16KB
    __shared__ unsigned short wT[192 * 64];   // [n][64k] swizzled, 24KB
    const int t = threadIdx.x;
    const int w = t >> 6, l = t & 63, G = l >> 4, c = l & 15;
    const size_t row0 = (size_t)blockIdx.x * 128;

    f32x4 acc[2][12];
#pragma unroll
    for (int i = 0; i < 2; i++)
#pragma unroll
        for (int j = 0; j < 12; j++) acc[i][j] = (f32x4){0.f, 0.f, 0.f, 0.f};

    for (int k0 = 0; k0 < 256; k0 += 64) {
        __syncthreads();
#pragma unroll
        for (int it = 0; it < 4; it++) {           // x tile: 128 rows x 8 slots
            int u = it * 256 + t, r = u >> 3, s = u & 7;
            const float* px = x + (row0 + r) * 256 + k0 + s * 8;
            float4 a = *(const float4*)px;
            float4 bq = *(const float4*)(px + 4);
            uint4 v;
            v.x = (unsigned)f2b(a.x) | ((unsigned)f2b(a.y) << 16);
            v.y = (unsigned)f2b(a.z) | ((unsigned)f2b(a.w) << 16);
            v.z = (unsigned)f2b(bq.x) | ((unsigned)f2b(bq.y) << 16);
            v.w = (unsigned)f2b(bq.z) | ((unsigned)f2b(bq.w) << 16);
            *(uint4*)((char*)xT + r * 128 + ((s * 16) ^ ((r & 7) << 4))) = v;
        }
#pragma unroll
        for (int it = 0; it < 6; it++) {           // W tile: 192 rows x 8 slots
            int u = it * 256 + t, r = u >> 3, s = u & 7;
            uint4 v = *(const uint4*)(WT + r * 256 + k0 + s * 8);
            *(uint4*)((char*)wT + r * 128 + ((s * 16) ^ ((r & 7) << 4))) = v;
        }
        __syncthreads();
#pragma unroll
        for (int kin = 0; kin < 2; kin++) {
            int m0r = (2 * w) * 16 + c, m1r = (2 * w + 1) * 16 + c;
            bf16x8 a0 = *(const bf16x8*)((char*)xT + m0r * 128 + ((kin * 64 + G * 16) ^ ((m0r & 7) << 4)));
            bf16x8 a1 = *(const bf16x8*)((char*)xT + m1r * 128 + ((kin * 64 + G * 16) ^ ((m1r & 7) << 4)));
#pragma unroll
            for (int nt = 0; nt < 12; nt++) {
                int nr = nt * 16 + c;
                bf16x8 bv = *(const bf16x8*)((char*)wT + nr * 128 + ((kin * 64 + G * 16) ^ ((nr & 7) << 4)));
                acc[0][nt] = MFMA16(a0, bv, acc[0][nt]);
                acc[1][nt] = MFMA16(a1, bv, acc[1][nt]);
            }
        }
    }
#pragma unroll
    for (int mt = 0; mt < 2; mt++)
#pragma unroll
        for (int nt = 0; nt < 12; nt++)
#pragma unroll
            for (int i = 0; i < 4; i++) {
                size_t row = row0 + (2 * w + mt) * 16 + 4 * G + i;
                unsigned short v = f2b(acc[mt][nt][i]);
                if (nt < 2)      theta_b[row * 32 + nt * 16 + c] = v;
                else if (nt < 4) phi_b[row * 32 + (nt - 2) * 16 + c] = v;
                else             g_b[row * 128 + (nt - 4) * 16 + c] = v;
            }
}

// ---------------------------------------------------------------------------
// K2: pool. blocks [0,1024): phi -> phi_p [b][1024][32] (plain layout)
//          blocks [1024,1536): g -> pooled, transposed, k-slot-permuted g_pT:
//            within each 32-m group, position p = 8*gg + 4*h + i holds
//            m_local = 16h + 4gg + i  (PV B-frag = 16 contiguous bytes). No XOR.
// ---------------------------------------------------------------------------
__global__ __launch_bounds__(256) void k_pool(
    const unsigned short* __restrict__ phi_b, const unsigned short* __restrict__ g_b,
    unsigned short* __restrict__ phi_p, unsigned short* __restrict__ g_pT)
{
    const int bid = blockIdx.x, t = threadIdx.x;
    if (bid < 1024) {
        const unsigned int* p32 = (const unsigned int*)phi_b;
        unsigned int* pp32 = (unsigned int*)phi_p;
        int idx = bid * 256 + t;
        int b = idx >> 14, r = idx & 16383, pm = r >> 4, d2 = r & 15;
        int hp = pm >> 5, wp = pm & 31;
        size_t base = ((size_t)b * 4096 + (2 * hp) * 64 + 2 * wp) * 16 + d2;
        unsigned v0 = p32[base], v1 = p32[base + 16], v2 = p32[base + 1024], v3 = p32[base + 1040];
        float lo = fmaxf(fmaxf(blo(v0), blo(v1)), fmaxf(blo(v2), blo(v3)));
        float hi = fmaxf(fmaxf(bhi(v0), bhi(v1)), fmaxf(bhi(v2), bhi(v3)));
        pp32[idx] = (unsigned)f2b(lo) | ((unsigned)f2b(hi) << 16);
    } else {
        __shared__ unsigned short P[32 * 128];   // [wp][128 d], rows 256B, swz key (wp&7)<<4
        int b = (bid - 1024) >> 5, hp = (bid - 1024) & 31;
        const unsigned int* g32 = (const unsigned int*)g_b;
#pragma unroll
        for (int it = 0; it < 8; it++) {
            int u = it * 256 + t, wp = u >> 6, d2 = u & 63;
            size_t base = ((size_t)b * 4096 + (2 * hp) * 64 + 2 * wp) * 64 + d2;
            unsigned v0 = g32[base], v1 = g32[base + 64], v2 = g32[base + 4096], v3 = g32[base + 4160];
            float lo = fmaxf(fmaxf(blo(v0), blo(v1)), fmaxf(blo(v2), blo(v3)));
            float hi = fmaxf(fmaxf(bhi(v0), bhi(v1)), fmaxf(bhi(v2), bhi(v3)));
            unsigned pv = (unsigned)f2b(lo) | ((unsigned)f2b(hi) << 16);
            *(unsigned*)((char*)P + wp * 256 + ((d2 * 4) ^ ((wp & 7) << 4))) = pv;
        }
        __syncthreads();
#pragma unroll
        for (int it = 0; it < 2; it++) {
            int d = t & 127, s4 = (t >> 7) + it * 2;   // s4 = gg (position block)
            union { unsigned short v[8]; uint4 q; } pk;
#pragma unroll
            for (int k = 0; k < 8; k++) {
                // position p = s4*8 + k holds m_local = 16*(k>>2) + 4*s4 + (k&3)
                int wp = 16 * (k >> 2) + 4 * s4 + (k & 3);
                pk.v[k] = *(const unsigned short*)((char*)P + wp * 256 + ((d * 2) ^ ((wp & 7) << 4)));
            }
            *(uint4*)(g_pT + ((size_t)b * 128 + d) * 1024 + hp * 32 + s4 * 8) = pk.q;
        }
    }
}

// ---------------------------------------------------------------------------
// K3: fused flash attention. 1024 blocks x 256 thr. 4 waves = 2 qg x 2 mg.
// Wave (qg,mg): 32q x 512m as 16 chunks of 32m. Per-mg double-buffered
// global_load_lds staging (counted vmcnt(5)). Partial-O combine, then w_o.
// ---------------------------------------------------------------------------
__global__ __launch_bounds__(256, 4) void k_attn(
    const unsigned short* __restrict__ theta_b, const unsigned short* __restrict__ phi_p,
    const unsigned short* __restrict__ g_pT, const unsigned short* __restrict__ woT,
    const float* __restrict__ x, const float* __restrict__ b_o,
    const float* __restrict__ sigma_p, float* __restrict__ out)
{
    // main: buf(mg,bi) @ mg*20480 + bi*10240: g 8KB [128d][64B], phi @+8192 2KB [32m][64B]
    // theta prologue @10240 (4KB). Combine: partial-O qg @ qg*16640 (32r x 520B),
    // ps @33280 (256B). Then: O rows r at (r>>5)*16640 + (r&31)*256 (+swz);
    // wo_l @8448 (8KB slices). Total 40960.
    __shared__ char lds[40960];

    const int t = threadIdx.x;
    const int w = t >> 6, l = t & 63, G = l >> 4, c = l & 15;
    const int qg = w >> 1, mg = w & 1;
    const int bid = (blockIdx.x & 7) * 128 + (blockIdx.x >> 3);   // XCD swizzle (bijective)
    const int b = bid >> 6;
    const int q0 = (bid & 63) * 64;
    const int xr = (c & 7) << 4;

    const unsigned short* gsrc = g_pT + (size_t)b * 131072;
    const unsigned short* psrc = phi_p + (size_t)b * 32768;
    // per wave per chunk: 4 g-loads + 1 phi-load -> counted vmcnt(5)
#define STAGE(BI, MC)                                                               \
    {                                                                               \
        char* gb = lds + mg * 20480 + (BI) * 10240;                                 \
        char* pb = gb + 8192;                                                       \
        const int hp = mg * 16 + (MC);                                              \
        _Pragma("unroll")                                                           \
        for (int it = 0; it < 4; it++) {                                            \
            int d = 64 * qg + 16 * it + (l >> 2);                                   \
            GLOAD16(gsrc + (size_t)d * 1024 + hp * 32 + (l & 3) * 8,                \
                    gb + qg * 4096 + it * 1024 + l * 16);                           \
        }                                                                           \
        {                                                                           \
            int r = 16 * qg + (l >> 2);                                             \
            GLOAD16(psrc + (size_t)(hp * 32 + r) * 32 + (l & 3) * 8,                \
                    pb + qg * 1024 + l * 16);                                       \
        }                                                                           \
    }

    // prologue: stage chunk 0 (both mg) + theta [64q][32ch] plain @10240
    STAGE(0, 0);
    {
        char* th = lds + 10240;
        int r = t >> 2, s = t & 3;
        uint4 v = *(const uint4*)(theta_b + ((size_t)(b * 4096 + q0 + r)) * 32 + s * 8);
        *(uint4*)(th + r * 64 + s * 16) = v;
    }
    __syncthreads();   // chunk0 + theta landed

    // wave's theta B-frags: q-tiles qg*32 and qg*32+16 (dense reads, no swz)
    const bf16x8 bt0 = *(const bf16x8*)(lds + 10240 + (qg * 32 + c) * 64 + G * 16);
    const bf16x8 bt1 = *(const bf16x8*)(lds + 10240 + (qg * 32 + 16 + c) * 64 + G * 16);
    __syncthreads();   // bt reads done before mc=0 stages buf1 (overwrites theta)

    f32x4 oacc[2][8];
#pragma unroll
    for (int qt = 0; qt < 2; qt++)
#pragma unroll
        for (int dt = 0; dt < 8; dt++) oacc[qt][dt] = (f32x4){0.f, 0.f, 0.f, 0.f};
    float ps[2] = {0.f, 0.f};
    const f32x4 zf = (f32x4){0.f, 0.f, 0.f, 0.f};

    for (int mc = 0; mc < 16; mc++) {
        const int cur = mc & 1;
        if (mc < 15) {
            STAGE(cur ^ 1, mc + 1);
            asm volatile("s_waitcnt vmcnt(5)" ::: "memory");   // cur's 5 landed
        } else {
            asm volatile("s_waitcnt vmcnt(0)" ::: "memory");
        }
        __builtin_amdgcn_sched_barrier(0);
        __builtin_amdgcn_s_barrier();
        __builtin_amdgcn_sched_barrier(0);

        const char* gL   = lds + mg * 20480 + cur * 10240;
        const char* phiL = gL + 8192;

        // S^T = phi @ theta^T (K=32 ch, one MFMA per m-tile x q-tile)
        bf16x8 ap0 = *(const bf16x8*)(phiL + c * 64 + G * 16);
        bf16x8 ap1 = *(const bf16x8*)(phiL + (16 + c) * 64 + G * 16);
        f32x4 sacc[2][2];
        __builtin_amdgcn_s_setprio(1);
        sacc[0][0] = MFMA16(ap0, bt0, zf);
        sacc[0][1] = MFMA16(ap1, bt0, zf);
        sacc[1][0] = MFMA16(ap0, bt1, zf);
        sacc[1][1] = MFMA16(ap1, bt1, zf);
        __builtin_amdgcn_s_setprio(0);

        // exp -> packed P A-frags (slot j = 4*mt + i <-> m = 16mt+4G+i) + rowsums
        bf16x8 pa[2];
#pragma unroll
        for (int qt = 0; qt < 2; qt++) {
            union { unsigned u[4]; bf16x8 v; } pu;
#pragma unroll
            for (int mt = 0; mt < 2; mt++)
#pragma unroll
                for (int hf = 0; hf < 2; hf++) {
                    float p0 = __expf(sacc[qt][mt][2 * hf]);
                    float p1 = __expf(sacc[qt][mt][2 * hf + 1]);
                    ps[qt] += p0 + p1;
                    pu.u[mt * 2 + hf] = (unsigned)f2b(p0) | ((unsigned)f2b(p1) << 16);
                }
            pa[qt] = pu.v;
        }

        // O += P @ g  (B-frag = one dense b128 per d-tile, feeds both q-tiles)
        __builtin_amdgcn_s_setprio(1);
#pragma unroll
        for (int dt = 0; dt < 8; dt++) {
            bf16x8 bg = *(const bf16x8*)(gL + (dt * 16 + c) * 64 + G * 16);
            oacc[0][dt] = MFMA16(pa[0], bg, oacc[0][dt]);
            oacc[1][dt] = MFMA16(pa[1], bg, oacc[1][dt]);
        }
        __builtin_amdgcn_s_setprio(0);

        asm volatile("s_waitcnt lgkmcnt(0)" ::: "memory");
        __builtin_amdgcn_sched_barrier(0);
        __builtin_amdgcn_s_barrier();                       // safe to overwrite cur
        __builtin_amdgcn_sched_barrier(0);
    }
#undef STAGE

    // wave-level rowsum reduce: lanes {c,c+16,c+32,c+48} -> total for q-col c
#pragma unroll
    for (int qt = 0; qt < 2; qt++) {
        ps[qt] += __shfl_xor(ps[qt], 16);
        ps[qt] += __shfl_xor(ps[qt], 32);
    }

    // ---- combine m-group partials ----
    if (mg == 1) {
        char* po = lds + qg * 16640;
#pragma unroll
        for (int qt = 0; qt < 2; qt++)
#pragma unroll
            for (int dt = 0; dt < 8; dt++)
#pragma unroll
                for (int i = 0; i < 4; i++)
                    *(float*)(po + (qt * 16 + 4 * G + i) * 520 + (dt * 16 + c) * 4) =
                        oacc[qt][dt][i];
        if (l < 16) {
            *(float*)(lds + 33280 + (qg * 32 + l) * 4)      = ps[0];
            *(float*)(lds + 33280 + (qg * 32 + 16 + l) * 4) = ps[1];
        }
    }
    __syncthreads();
    if (mg == 0) {
        const char* po = lds + qg * 16640;
#pragma unroll
        for (int qt = 0; qt < 2; qt++)
#pragma unroll
            for (int dt = 0; dt < 8; dt++) {
                f32x4 a = oacc[qt][dt];
#pragma unroll
                for (int i = 0; i < 4; i++)
                    a[i] += *(const float*)(po + (qt * 16 + 4 * G + i) * 520 + (dt * 16 + c) * 4);
                oacc[qt][dt] = a;
            }
#pragma unroll
        for (int qt = 0; qt < 2; qt++)
            ps[qt] += *(const float*)(lds + 33280 + (qg * 32 + qt * 16 + c) * 4);
        float rinv[2][4];
#pragma unroll
        for (int qt = 0; qt < 2; qt++)
#pragma unroll
            for (int i = 0; i < 4; i++)
                rinv[qt][i] = 1.0f / __shfl(ps[qt], 4 * G + i);
        // write normalized bf16 O rows (own region; all partial reads above done)
        char* Or = lds + qg * 16640;
#pragma unroll
        for (int qt = 0; qt < 2; qt++)
#pragma unroll
            for (int dt = 0; dt < 8; dt++)
#pragma unroll
                for (int i = 0; i < 4; i++) {
                    int r32 = qt * 16 + 4 * G + i, d = dt * 16 + c;
                    *(unsigned short*)(Or + r32 * 256 + ((d * 2) ^ ((r32 & 7) << 4))) =
                        f2b(oacc[qt][dt][i] * rinv[qt][i]);
                }
    }
    __syncthreads();   // O visible to all

    // ---- epilogue: out = x + sigma * (O @ w_o + b_o). Wave w: rows w*16..+16 ----
    const float sg = *sigma_p;
    const char* O_r = lds + (w >> 1) * 16640 + ((w & 1) * 16 + c) * 256;  // row w*16+c
    char* wo_l = lds + 8448;
    bf16x8 aO[4];
#pragma unroll
    for (int ks = 0; ks < 4; ks++)
        aO[ks] = *(const bf16x8*)(O_r + ((ks * 64 + G * 16) ^ xr));

    for (int cb = 0; cb < 8; cb++) {
        __syncthreads();                         // prev wo_l reads done
#pragma unroll
        for (int it = 0; it < 2; it++) {         // stage woT slice [32 c][128 d] = 8KB
            int u = it * 256 + t, r = u >> 4, s = u & 15;
            uint4 v = *(const uint4*)(woT + (size_t)(cb * 32 + r) * 128 + s * 8);
            *(uint4*)(wo_l + r * 256 + ((s * 16) ^ ((r & 7) << 4))) = v;
        }
        __syncthreads();
        f32x4 eacc[2];
#pragma unroll
        for (int ct = 0; ct < 2; ct++) eacc[ct] = (f32x4){0.f, 0.f, 0.f, 0.f};
#pragma unroll
        for (int ks = 0; ks < 4; ks++) {
#pragma unroll
            for (int ct = 0; ct < 2; ct++) {
                bf16x8 bw = *(const bf16x8*)(wo_l + (ct * 16 + c) * 256 + ((ks * 64 + G * 16) ^ xr));
                eacc[ct] = MFMA16(aO[ks], bw, eacc[ct]);
            }
        }
#pragma unroll
        for (int ct = 0; ct < 2; ct++) {
            int col = cb * 32 + ct * 16 + c;
            float bo = b_o[col];
#pragma unroll
            for (int i = 0; i < 4; i++) {
                size_t off = ((size_t)(b * 4096 + q0 + w * 16 + 4 * G + i)) * 256 + col;
                out[off] = x[off] + sg * (eacc[ct][i] + bo);
            }
        }
    }
}

// ---------------------------------------------------------------------------
extern "C" void kernel_launch(void* const* d_in, const int* in_sizes, int n_in,
                              void* d_out, int out_size, void* d_ws, size_t ws_size,
                              hipStream_t stream)
{
    const float* x       = (const float*)d_in[0];
    const float* w_theta = (const float*)d_in[1];
    const float* w_phi   = (const float*)d_in[2];
    const float* w_g     = (const float*)d_in[3];
    const float* w_o     = (const float*)d_in[4];
    const float* b_o     = (const float*)d_in[5];
    const float* sigma   = (const float*)d_in[6];
    float* out = (float*)d_out;

    char* ws = (char*)d_ws;
    unsigned short* theta_b = (unsigned short*)(ws);              //  4 MB [B,4096,32]
    unsigned short* phi_b   = (unsigned short*)(ws + 4194304);    //  4 MB [B,4096,32]
    unsigned short* g_b     = (unsigned short*)(ws + 8388608);    // 16 MB [B,4096,128]
    unsigned short* phi_p   = (unsigned short*)(ws + 25165824);   //  1 MB [B,1024,32] plain
    unsigned short* g_pT    = (unsigned short*)(ws + 26214400);   //  4 MB [B,128,1024] k-perm
    unsigned short* WT      = (unsigned short*)(ws + 30408704);   // 96 KB [192,256]
    unsigned short* woT     = (unsigned short*)(ws + 30507008);   // 64 KB [256,128]

    hipLaunchKernelGGL(k_prep, dim3(448), dim3(256), 0, stream,
                       w_theta, w_phi, w_g, w_o, WT, woT);
    hipLaunchKernelGGL(k_proj, dim3(512), dim3(256), 0, stream,
                       x, WT, theta_b, phi_b, g_b);
    hipLaunchKernelGGL(k_pool, dim3(1536), dim3(256), 0, stream,
                       phi_b, g_b, phi_p, g_pT);
    hipLaunchKernelGGL(k_attn, dim3(1024), dim3(256), 0, stream,
                       theta_b, phi_p, g_pT, woT, x, b_o, sigma, out);
}

// Round 9
// 69.757 us; speedup vs baseline: 1.6137x; 1.1105x over previous
//
#include <hip/hip_runtime.h>
#include <hip/hip_bf16.h>

// SNNonLocalBlock: B=16, H=W=64, C=256, L=4096, Ld=1024
// Round 9 = Round 8 with the __exp2f -> __builtin_amdgcn_exp2f compile fix.
// (1) k_attn 1-barrier-per-chunk schedule + exp2 fold (w_theta pre-scaled by
// log2e); (2) k_pool fused into k_proj (in-register ww-pool, LDS rr-pool,
// direct phi_p/g_pT emission) - kills a kernel + ~35MB HBM.

typedef __attribute__((ext_vector_type(8))) short bf16x8;
typedef __attribute__((ext_vector_type(4))) float f32x4;

#define MFMA16(A,B,C) __builtin_amdgcn_mfma_f32_16x16x32_bf16(A,B,C,0,0,0)

#define GLOAD16(GSRC, LDST)                                                        \
    __builtin_amdgcn_global_load_lds(                                              \
        (const __attribute__((address_space(1))) unsigned int*)(GSRC),             \
        (__attribute__((address_space(3))) unsigned int*)(LDST), 16, 0, 0)

static __device__ __forceinline__ unsigned short f2b(float f) {
    __hip_bfloat16 h = __float2bfloat16(f);
    return *reinterpret_cast<unsigned short*>(&h);
}
static __device__ __forceinline__ unsigned short bmax(unsigned short a, unsigned short b) {
    return (__uint_as_float((unsigned)a << 16) > __uint_as_float((unsigned)b << 16)) ? a : b;
}
static __device__ __forceinline__ float fexp2(float f) {
    return __builtin_amdgcn_exp2f(f);
}

// ---------------------------------------------------------------------------
// K0: prep: WT[192 n][256 k] bf16 = [w_theta*log2e | w_phi | w_g]^T ;
//           woT[256 c][128 d] bf16
// ---------------------------------------------------------------------------
__global__ void k_prep(const float* __restrict__ w_theta, const float* __restrict__ w_phi,
                       const float* __restrict__ w_g, const float* __restrict__ w_o,
                       unsigned short* __restrict__ WT, unsigned short* __restrict__ woT)
{
    int bid = blockIdx.x, t = threadIdx.x;
    if (bid < 192) {
        int n = bid;
        float v;
        if (n < 32)      v = w_theta[t * 32 + n] * 1.44269504f;  // fold log2e -> exp2
        else if (n < 64) v = w_phi[t * 32 + (n - 32)];
        else             v = w_g[t * 128 + (n - 64)];
        WT[n * 256 + t] = f2b(v);
    } else if (t < 128) {
        int cc = bid - 192;
        woT[cc * 128 + t] = f2b(w_o[t * 256 + cc]);
    }
}

// ---------------------------------------------------------------------------
// K1: fused proj + pool. 512 blocks x 128 rows; block bid = b*32 + h2 covers
// image rows {2h2, 2h2+1} x 64 cols. theta -> global full-res; phi/g pooled:
// ww-pairs maxed in-register (acc i/i+1), staged to LDS T[64][160] (512B rows,
// XOR (row&7)<<4), rr-pairs maxed from LDS -> phi_p [b][1024][32] and
// g_pT [b][128 d][1024 m] with the k-slot permute (p=8gg+4h+i <-> m=16h+4gg+i).
// ---------------------------------------------------------------------------
__global__ __launch_bounds__(256) void k_proj(
    const float* __restrict__ x, const unsigned short* __restrict__ WT,
    unsigned short* __restrict__ theta_b, unsigned short* __restrict__ phi_p,
    unsigned short* __restrict__ g_pT)
{
    __shared__ char plds[40960];
    unsigned short* xT = (unsigned short*)plds;            // [128][64k] swz, 16KB
    unsigned short* wT = (unsigned short*)(plds + 16384);  // [192][64k] swz, 24KB

    const int t = threadIdx.x;
    const int w = t >> 6, l = t & 63, G = l >> 4, c = l & 15;
    const int bid = blockIdx.x;
    const int b = bid >> 5, h2 = bid & 31;
    const size_t row0 = (size_t)bid * 128;

    f32x4 acc[2][12];
#pragma unroll
    for (int i = 0; i < 2; i++)
#pragma unroll
        for (int j = 0; j < 12; j++) acc[i][j] = (f32x4){0.f, 0.f, 0.f, 0.f};

    for (int k0 = 0; k0 < 256; k0 += 64) {
        __syncthreads();
#pragma unroll
        for (int it = 0; it < 4; it++) {           // x tile: 128 rows x 8 slots
            int u = it * 256 + t, r = u >> 3, s = u & 7;
            const float* px = x + (row0 + r) * 256 + k0 + s * 8;
            float4 a = *(const float4*)px;
            float4 bq = *(const float4*)(px + 4);
            uint4 v;
            v.x = (unsigned)f2b(a.x) | ((unsigned)f2b(a.y) << 16);
            v.y = (unsigned)f2b(a.z) | ((unsigned)f2b(a.w) << 16);
            v.z = (unsigned)f2b(bq.x) | ((unsigned)f2b(bq.y) << 16);
            v.w = (unsigned)f2b(bq.z) | ((unsigned)f2b(bq.w) << 16);
            *(uint4*)((char*)xT + r * 128 + ((s * 16) ^ ((r & 7) << 4))) = v;
        }
#pragma unroll
        for (int it = 0; it < 6; it++) {           // W tile: 192 rows x 8 slots
            int u = it * 256 + t, r = u >> 3, s = u & 7;
            uint4 v = *(const uint4*)(WT + r * 256 + k0 + s * 8);
            *(uint4*)((char*)wT + r * 128 + ((s * 16) ^ ((r & 7) << 4))) = v;
        }
        __syncthreads();
#pragma unroll
        for (int kin = 0; kin < 2; kin++) {
            int m0r = (2 * w) * 16 + c, m1r = (2 * w + 1) * 16 + c;
            bf16x8 a0 = *(const bf16x8*)((char*)xT + m0r * 128 + ((kin * 64 + G * 16) ^ ((m0r & 7) << 4)));
            bf16x8 a1 = *(const bf16x8*)((char*)xT + m1r * 128 + ((kin * 64 + G * 16) ^ ((m1r & 7) << 4)));
#pragma unroll
            for (int nt = 0; nt < 12; nt++) {
                int nr = nt * 16 + c;
                bf16x8 bv = *(const bf16x8*)((char*)wT + nr * 128 + ((kin * 64 + G * 16) ^ ((nr & 7) << 4)));
                acc[0][nt] = MFMA16(a0, bv, acc[0][nt]);
                acc[1][nt] = MFMA16(a1, bv, acc[1][nt]);
            }
        }
    }

    // theta -> global (full-res), nt 0..1
#pragma unroll
    for (int mt = 0; mt < 2; mt++)
#pragma unroll
        for (int nt = 0; nt < 2; nt++)
#pragma unroll
            for (int i = 0; i < 4; i++) {
                size_t row = row0 + (2 * w + mt) * 16 + 4 * G + i;
                theta_b[row * 32 + nt * 16 + c] = f2b(acc[mt][nt][i]);
            }

    __syncthreads();   // all MFMA reads of xT/wT done before overwrite

    // ww-pooled tile T[64 rows][160 cols]: row = rr*32 + wp, 512B stride,
    // byte = row*512 + ((2*col) ^ ((row&7)<<4)). value = max over ww pair.
#pragma unroll
    for (int mt = 0; mt < 2; mt++) {
        int rl = 2 * w + mt, rr = rl >> 2, wpb = (rl & 3) * 8 + 2 * G;
#pragma unroll
        for (int nt = 2; nt < 12; nt++) {
            int col = (nt - 2) * 16 + c;
#pragma unroll
            for (int j = 0; j < 2; j++) {
                int row = rr * 32 + wpb + j;
                float m = fmaxf(acc[mt][nt][2 * j], acc[mt][nt][2 * j + 1]);
                *(unsigned short*)(plds + row * 512 + ((2 * col) ^ ((row & 7) << 4))) = f2b(m);
            }
        }
    }
    __syncthreads();

    // phi: rr-pool cols 0..31 -> phi_p[b][h2*32+wp][ch]
    {
        int wp = t >> 3, chb = (t & 7) * 4;
        unsigned short vv[4];
#pragma unroll
        for (int k = 0; k < 4; k++) {
            int colb = 2 * (chb + k);
            unsigned short a = *(const unsigned short*)(plds + wp * 512 + (colb ^ ((wp & 7) << 4)));
            unsigned short e = *(const unsigned short*)(plds + (wp + 32) * 512 + (colb ^ ((wp & 7) << 4)));
            vv[k] = bmax(a, e);
        }
        uint2 pv;
        pv.x = (unsigned)vv[0] | ((unsigned)vv[1] << 16);
        pv.y = (unsigned)vv[2] | ((unsigned)vv[3] << 16);
        *(uint2*)(phi_p + ((size_t)(b * 1024 + h2 * 32 + wp)) * 32 + chb) = pv;
    }
    // g: rr-pool cols 32..159, transpose + k-perm -> g_pT[b][d][h2*32 + s4*8 + k]
#pragma unroll
    for (int it = 0; it < 2; it++) {
        int d = t & 127, s4 = (t >> 7) + 2 * it;
        union { unsigned short v[8]; uint4 q; } pk;
#pragma unroll
        for (int k = 0; k < 8; k++) {
            int wp2 = 16 * (k >> 2) + 4 * s4 + (k & 3);
            int colb = 2 * (32 + d);
            unsigned short a = *(const unsigned short*)(plds + wp2 * 512 + (colb ^ ((wp2 & 7) << 4)));
            unsigned short e = *(const unsigned short*)(plds + (wp2 + 32) * 512 + (colb ^ ((wp2 & 7) << 4)));
            pk.v[k] = bmax(a, e);
        }
        *(uint4*)(g_pT + ((size_t)b * 128 + d) * 1024 + h2 * 32 + s4 * 8) = pk.q;
    }
}

// ---------------------------------------------------------------------------
// K3: fused flash attention. 1024 blocks x 256 thr. 4 waves = 2 qg x 2 mg.
// Wave (qg,mg): 32q x 512m as 16 chunks of 32m. ONE barrier per chunk:
// vmcnt(0) -> barrier (data-ready + overwrite-safe) -> STAGE(next) -> compute.
// ---------------------------------------------------------------------------
__global__ __launch_bounds__(256, 4) void k_attn(
    const unsigned short* __restrict__ theta_b, const unsigned short* __restrict__ phi_p,
    const unsigned short* __restrict__ g_pT, const unsigned short* __restrict__ woT,
    const float* __restrict__ x, const float* __restrict__ b_o,
    const float* __restrict__ sigma_p, float* __restrict__ out)
{
    // main: buf(mg,bi) @ mg*20480 + bi*10240: g 8KB [128d][64B], phi @+8192 2KB
    // theta prologue @10240. Combine: partial-O qg @ qg*16640 (32r x 520B),
    // ps @33280. Epilogue: O rows @ qg*16640 (8KB), wo_l @8448. Total 40960.
    __shared__ char lds[40960];

    const int t = threadIdx.x;
    const int w = t >> 6, l = t & 63, G = l >> 4, c = l & 15;
    const int qg = w >> 1, mg = w & 1;
    const int bid = (blockIdx.x & 7) * 128 + (blockIdx.x >> 3);   // XCD swizzle (bijective)
    const int b = bid >> 6;
    const int q0 = (bid & 63) * 64;
    const int xr = (c & 7) << 4;

    const unsigned short* gsrc = g_pT + (size_t)b * 131072;
    const unsigned short* psrc = phi_p + (size_t)b * 32768;
    // per wave per chunk: 4 g-loads + 1 phi-load
#define STAGE(BI, MC)                                                               \
    {                                                                               \
        char* gb = lds + mg * 20480 + (BI) * 10240;                                 \
        char* pb = gb + 8192;                                                       \
        const int hp = mg * 16 + (MC);                                              \
        _Pragma("unroll")                                                           \
        for (int it = 0; it < 4; it++) {                                            \
            int d = 64 * qg + 16 * it + (l >> 2);                                   \
            GLOAD16(gsrc + (size_t)d * 1024 + hp * 32 + (l & 3) * 8,                \
                    gb + qg * 4096 + it * 1024 + l * 16);                           \
        }                                                                           \
        {                                                                           \
            int r = 16 * qg + (l >> 2);                                             \
            GLOAD16(psrc + (size_t)(hp * 32 + r) * 32 + (l & 3) * 8,                \
                    pb + qg * 1024 + l * 16);                                       \
        }                                                                           \
    }

    // prologue: stage chunk 0 (both mg) + theta [64q][32ch] plain @10240
    STAGE(0, 0);
    {
        char* th = lds + 10240;
        int r = t >> 2, s = t & 3;
        uint4 v = *(const uint4*)(theta_b + ((size_t)(b * 4096 + q0 + r)) * 32 + s * 8);
        *(uint4*)(th + r * 64 + s * 16) = v;
    }
    __syncthreads();   // chunk0 + theta landed (drains vmcnt+lgkm)

    // wave's theta B-frags (dense reads, no swz)
    const bf16x8 bt0 = *(const bf16x8*)(lds + 10240 + (qg * 32 + c) * 64 + G * 16);
    const bf16x8 bt1 = *(const bf16x8*)(lds + 10240 + (qg * 32 + 16 + c) * 64 + G * 16);
    __syncthreads();   // bt reads done before iter0 stages buf1 (overwrites theta)

    f32x4 oacc[2][8];
#pragma unroll
    for (int qt = 0; qt < 2; qt++)
#pragma unroll
        for (int dt = 0; dt < 8; dt++) oacc[qt][dt] = (f32x4){0.f, 0.f, 0.f, 0.f};
    float ps[2] = {0.f, 0.f};
    const f32x4 zf = (f32x4){0.f, 0.f, 0.f, 0.f};

    for (int mc = 0; mc < 16; mc++) {
        const int cur = mc & 1;
        // my chunk-mc loads landed; barrier => everyone's landed AND everyone
        // finished compute(mc-1) => buf[cur^1] is free to overwrite.
        asm volatile("s_waitcnt vmcnt(0)" ::: "memory");
        __builtin_amdgcn_sched_barrier(0);
        __builtin_amdgcn_s_barrier();
        __builtin_amdgcn_sched_barrier(0);
        if (mc < 15) STAGE(cur ^ 1, mc + 1);    // lands under compute(mc)

        const char* gL   = lds + mg * 20480 + cur * 10240;
        const char* phiL = gL + 8192;

        // S^T = phi @ theta^T (K=32 ch)
        bf16x8 ap0 = *(const bf16x8*)(phiL + c * 64 + G * 16);
        bf16x8 ap1 = *(const bf16x8*)(phiL + (16 + c) * 64 + G * 16);
        f32x4 sacc[2][2];
        __builtin_amdgcn_s_setprio(1);
        sacc[0][0] = MFMA16(ap0, bt0, zf);
        sacc[0][1] = MFMA16(ap1, bt0, zf);
        sacc[1][0] = MFMA16(ap0, bt1, zf);
        sacc[1][1] = MFMA16(ap1, bt1, zf);
        __builtin_amdgcn_s_setprio(0);

        // exp2 (theta pre-scaled by log2e) -> packed P A-frags + rowsums
        bf16x8 pa[2];
#pragma unroll
        for (int qt = 0; qt < 2; qt++) {
            union { unsigned u[4]; bf16x8 v; } pu;
#pragma unroll
            for (int mt = 0; mt < 2; mt++)
#pragma unroll
                for (int hf = 0; hf < 2; hf++) {
                    float p0 = fexp2(sacc[qt][mt][2 * hf]);
                    float p1 = fexp2(sacc[qt][mt][2 * hf + 1]);
                    ps[qt] += p0 + p1;
                    pu.u[mt * 2 + hf] = (unsigned)f2b(p0) | ((unsigned)f2b(p1) << 16);
                }
            pa[qt] = pu.v;
        }

        // O += P @ g  (B-frag = one dense b128 per d-tile, feeds both q-tiles)
        __builtin_amdgcn_s_setprio(1);
#pragma unroll
        for (int dt = 0; dt < 8; dt++) {
            bf16x8 bg = *(const bf16x8*)(gL + (dt * 16 + c) * 64 + G * 16);
            oacc[0][dt] = MFMA16(pa[0], bg, oacc[0][dt]);
            oacc[1][dt] = MFMA16(pa[1], bg, oacc[1][dt]);
        }
        __builtin_amdgcn_s_setprio(0);
    }
#undef STAGE
    __syncthreads();   // all compute(15) reads done before combine overwrites lds

    // wave-level rowsum reduce: lanes {c,c+16,c+32,c+48} -> total for q-col c
#pragma unroll
    for (int qt = 0; qt < 2; qt++) {
        ps[qt] += __shfl_xor(ps[qt], 16);
        ps[qt] += __shfl_xor(ps[qt], 32);
    }

    // ---- combine m-group partials ----
    if (mg == 1) {
        char* po = lds + qg * 16640;
#pragma unroll
        for (int qt = 0; qt < 2; qt++)
#pragma unroll
            for (int dt = 0; dt < 8; dt++)
#pragma unroll
                for (int i = 0; i < 4; i++)
                    *(float*)(po + (qt * 16 + 4 * G + i) * 520 + (dt * 16 + c) * 4) =
                        oacc[qt][dt][i];
        if (l < 16) {
            *(float*)(lds + 33280 + (qg * 32 + l) * 4)      = ps[0];
            *(float*)(lds + 33280 + (qg * 32 + 16 + l) * 4) = ps[1];
        }
    }
    __syncthreads();
    if (mg == 0) {
        const char* po = lds + qg * 16640;
#pragma unroll
        for (int qt = 0; qt < 2; qt++)
#pragma unroll
            for (int dt = 0; dt < 8; dt++) {
                f32x4 a = oacc[qt][dt];
#pragma unroll
                for (int i = 0; i < 4; i++)
                    a[i] += *(const float*)(po + (qt * 16 + 4 * G + i) * 520 + (dt * 16 + c) * 4);
                oacc[qt][dt] = a;
            }
#pragma unroll
        for (int qt = 0; qt < 2; qt++)
            ps[qt] += *(const float*)(lds + 33280 + (qg * 32 + qt * 16 + c) * 4);
        float rinv[2][4];
#pragma unroll
        for (int qt = 0; qt < 2; qt++)
#pragma unroll
            for (int i = 0; i < 4; i++)
                rinv[qt][i] = 1.0f / __shfl(ps[qt], 4 * G + i);
        // write normalized bf16 O rows
        char* Or = lds + qg * 16640;
#pragma unroll
        for (int qt = 0; qt < 2; qt++)
#pragma unroll
            for (int dt = 0; dt < 8; dt++)
#pragma unroll
                for (int i = 0; i < 4; i++) {
                    int r32 = qt * 16 + 4 * G + i, d = dt * 16 + c;
                    *(unsigned short*)(Or + r32 * 256 + ((d * 2) ^ ((r32 & 7) << 4))) =
                        f2b(oacc[qt][dt][i] * rinv[qt][i]);
                }
    }
    __syncthreads();   // O visible to all

    // ---- epilogue: out = x + sigma * (O @ w_o + b_o). Wave w: rows w*16..+16 ----
    const float sg = *sigma_p;
    const char* O_r = lds + (w >> 1) * 16640 + ((w & 1) * 16 + c) * 256;  // row w*16+c
    char* wo_l = lds + 8448;
    bf16x8 aO[4];
#pragma unroll
    for (int ks = 0; ks < 4; ks++)
        aO[ks] = *(const bf16x8*)(O_r + ((ks * 64 + G * 16) ^ xr));

    for (int cb = 0; cb < 8; cb++) {
        __syncthreads();                         // prev wo_l reads done
#pragma unroll
        for (int it = 0; it < 2; it++) {         // stage woT slice [32 c][128 d] = 8KB
            int u = it * 256 + t, r = u >> 4, s = u & 15;
            uint4 v = *(const uint4*)(woT + (size_t)(cb * 32 + r) * 128 + s * 8);
            *(uint4*)(wo_l + r * 256 + ((s * 16) ^ ((r & 7) << 4))) = v;
        }
        __syncthreads();
        f32x4 eacc[2];
#pragma unroll
        for (int ct = 0; ct < 2; ct++) eacc[ct] = (f32x4){0.f, 0.f, 0.f, 0.f};
#pragma unroll
        for (int ks = 0; ks < 4; ks++) {
#pragma unroll
            for (int ct = 0; ct < 2; ct++) {
                bf16x8 bw = *(const bf16x8*)(wo_l + (ct * 16 + c) * 256 + ((ks * 64 + G * 16) ^ xr));
                eacc[ct] = MFMA16(aO[ks], bw, eacc[ct]);
            }
        }
#pragma unroll
        for (int ct = 0; ct < 2; ct++) {
            int col = cb * 32 + ct * 16 + c;
            float bo = b_o[col];
#pragma unroll
            for (int i = 0; i < 4; i++) {
                size_t off = ((size_t)(b * 4096 + q0 + w * 16 + 4 * G + i)) * 256 + col;
                out[off] = x[off] + sg * (eacc[ct][i] + bo);
            }
        }
    }
}

// ---------------------------------------------------------------------------
extern "C" void kernel_launch(void* const* d_in, const int* in_sizes, int n_in,
                              void* d_out, int out_size, void* d_ws, size_t ws_size,
                              hipStream_t stream)
{
    const float* x       = (const float*)d_in[0];
    const float* w_theta = (const float*)d_in[1];
    const float* w_phi   = (const float*)d_in[2];
    const float* w_g     = (const float*)d_in[3];
    const float* w_o     = (const float*)d_in[4];
    const float* b_o     = (const float*)d_in[5];
    const float* sigma   = (const float*)d_in[6];
    float* out = (float*)d_out;

    char* ws = (char*)d_ws;
    unsigned short* theta_b = (unsigned short*)(ws);              //  4 MB [B,4096,32]
    unsigned short* phi_p   = (unsigned short*)(ws + 4194304);    //  1 MB [B,1024,32]
    unsigned short* g_pT    = (unsigned short*)(ws + 5242880);    //  4 MB [B,128,1024] k-perm
    unsigned short* WT      = (unsigned short*)(ws + 9437184);    // 96 KB [192,256]
    unsigned short* woT     = (unsigned short*)(ws + 9535488);    // 64 KB [256,128]

    hipLaunchKernelGGL(k_prep, dim3(448), dim3(256), 0, stream,
                       w_theta, w_phi, w_g, w_o, WT, woT);
    hipLaunchKernelGGL(k_proj, dim3(512), dim3(256), 0, stream,
                       x, WT, theta_b, phi_p, g_pT);
    hipLaunchKernelGGL(k_attn, dim3(1024), dim3(256), 0, stream,
                       theta_b, phi_p, g_pT, woT, x, b_o, sigma, out);
}